// Round 1
// baseline (344.363 us; speedup 1.0000x reference)
//
#include <hip/hip_runtime.h>
#include <cstdint>
#include <math.h>

#define Nn   16
#define Cc   64
#define Ww   512
#define Hh   512
#define RED  64
#define OUTW 128

// ---------------------------------------------------------------------------
// Kernel 1: pooled[n][w] = max over (c,h) of x[n][c][w][h]
// One block per (n,w). Reads 64 rows of 2KB each, float4-vectorized.
// ---------------------------------------------------------------------------
__global__ void pool_kernel(const float* __restrict__ x, float* __restrict__ pooled) {
    const int b = blockIdx.x;            // n*512 + w
    const int n = b >> 9;
    const int w = b & 511;
    const float* base = x + ((size_t)n * Cc * Ww + w) * Hh;   // x[n][0][w][0]
    const int tid = threadIdx.x;
    float m = -INFINITY;
    #pragma unroll 4
    for (int i = tid; i < Cc * (Hh / 4); i += 256) {
        const int c = i >> 7;            // 0..63
        const int f = i & 127;           // float4 index within row
        const float4 v = *reinterpret_cast<const float4*>(base + (size_t)c * (Ww * Hh) + f * 4);
        m = fmaxf(fmaxf(fmaxf(m, v.x), fmaxf(v.y, v.z)), v.w);
    }
    #pragma unroll
    for (int off = 32; off > 0; off >>= 1)
        m = fmaxf(m, __shfl_down(m, off, 64));
    __shared__ float red[4];
    if ((tid & 63) == 0) red[tid >> 6] = m;
    __syncthreads();
    if (tid == 0)
        pooled[b] = fmaxf(fmaxf(red[0], red[1]), fmaxf(red[2], red[3]));
}

// ---------------------------------------------------------------------------
// Kernel 2: MLP + BatchNorm(batch stats) + ReLU + logits + top-128 select.
// 16 blocks (one per batch row n); every block redundantly computes the full
// h[16][64] + BN stats (cheap, deterministic, identical across blocks), then
// computes only its own row's logits and does rank-based top-k.
// Softmax is skipped: strictly monotone per row -> same top-k set.
// Tie-break matches jax.lax.top_k: (value desc, index asc) strict total order.
// ---------------------------------------------------------------------------
__global__ void __launch_bounds__(512) mlp_topk_kernel(
    const float* __restrict__ pooled,   // [16][512]
    const float* __restrict__ w1,       // [64][512]
    const float* __restrict__ b1,       // [64]
    const float* __restrict__ gamma,    // [64]
    const float* __restrict__ beta,     // [64]
    const float* __restrict__ w2,       // [512][64]
    const float* __restrict__ b2,       // [512]
    int* __restrict__ idx_out)          // [16][128]
{
    const int row = blockIdx.x;         // batch row this block owns for top-k
    const int tid = threadIdx.x;

    __shared__ float pooled_t[Ww][Nn + 1];   // transposed + padded (bank-spread)
    __shared__ float hbn_t[RED][Nn + 1];     // h, later BN+ReLU'd, [r][n]
    __shared__ float mu_s[RED], is_s[RED];
    __shared__ float logits_row[Ww];
    __shared__ unsigned long long sel_mask[Ww / 64];

    // stage pooled transposed into LDS
    for (int i = tid; i < Nn * Ww; i += 512) {
        const int n = i >> 9, k = i & 511;
        pooled_t[k][n] = pooled[i];
    }
    __syncthreads();

    // h[n][r] = pooled[n,:] . w1[r,:] + b1[r]   (1024 entries, 2 per thread)
    float hv[2];
    int hn[2], hr[2];
    #pragma unroll
    for (int e = 0; e < 2; ++e) {
        const int item = e * 512 + tid;
        const int n = item & 15, r = item >> 4;   // wave: 16 lanes share one w1 row
        hn[e] = n; hr[e] = r;
        float acc = b1[r];
        for (int k = 0; k < Ww; ++k)
            acc += pooled_t[k][n] * w1[r * Ww + k];
        hv[e] = acc;
    }
    #pragma unroll
    for (int e = 0; e < 2; ++e) hbn_t[hr[e]][hn[e]] = hv[e];
    __syncthreads();

    // BatchNorm1d training-mode stats over the batch (N=16), biased variance
    if (tid < RED) {
        float s = 0.f, s2 = 0.f;
        #pragma unroll
        for (int n = 0; n < Nn; ++n) { const float v = hbn_t[tid][n]; s += v; s2 += v * v; }
        const float mu  = s  * (1.f / Nn);
        const float var = s2 * (1.f / Nn) - mu * mu;
        mu_s[tid] = mu;
        is_s[tid] = 1.f / sqrtf(var + 1e-5f);
    }
    __syncthreads();

    // normalize + ReLU
    #pragma unroll
    for (int e = 0; e < 2; ++e) {
        const int r = hr[e], n = hn[e];
        const float v = gamma[r] * (hv[e] - mu_s[r]) * is_s[r] + beta[r];
        hbn_t[r][n] = fmaxf(v, 0.f);
    }
    __syncthreads();

    // logits for this block's row only: logits[w] = hbn[row,:] . w2[w,:] + b2[w]
    {
        const int w = tid;
        float acc = b2[w];
        #pragma unroll
        for (int r = 0; r < RED; ++r)
            acc += hbn_t[r][row] * w2[w * RED + r];
        logits_row[w] = acc;
    }
    __syncthreads();

    // rank-based top-128: rank = #{ww : u>v or (u==v and ww<w)}; select rank<128.
    // Output position = #selected with smaller w  -> indices sorted ascending.
    {
        const int w = tid;
        const float v = logits_row[w];
        int rank = 0;
        for (int ww = 0; ww < Ww; ++ww) {
            const float u = logits_row[ww];            // LDS broadcast (uniform addr)
            rank += (u > v || (u == v && ww < w)) ? 1 : 0;
        }
        const bool sel = (rank < OUTW);
        const unsigned long long m = __ballot(sel);    // lanes = consecutive w
        if ((tid & 63) == 0) sel_mask[tid >> 6] = m;
        __syncthreads();
        if (sel) {
            int pos = 0;
            #pragma unroll
            for (int bb = 0; bb < (Ww / 64); ++bb)
                if (bb < (w >> 6)) pos += __popcll(sel_mask[bb]);
            pos += __popcll(sel_mask[w >> 6] & ((1ULL << (w & 63)) - 1ULL));
            idx_out[row * OUTW + pos] = w;
        }
    }
}

// ---------------------------------------------------------------------------
// Kernel 3: out[n][c][j][h] = x[n][c][idx[n][j]][h]
// One block per (n,j); moves 64 rows of 2KB each, float4-vectorized.
// ---------------------------------------------------------------------------
__global__ void gather_kernel(const float* __restrict__ x,
                              const int* __restrict__ idx,
                              float* __restrict__ out) {
    const int b = blockIdx.x;            // n*128 + j
    const int n = b >> 7;
    const int j = b & 127;
    const int w = idx[b];
    const float* src = x   + ((size_t)n * Cc * Ww   + w) * Hh;   // + c*Ww*Hh
    float*       dst = out + ((size_t)n * Cc * OUTW + j) * Hh;   // + c*OUTW*Hh
    const int tid = threadIdx.x;
    #pragma unroll 4
    for (int i = tid; i < Cc * (Hh / 4); i += 256) {
        const int c = i >> 7;
        const int f = i & 127;
        const float4 v = *reinterpret_cast<const float4*>(src + (size_t)c * (Ww * Hh) + f * 4);
        *reinterpret_cast<float4*>(dst + (size_t)c * (OUTW * Hh) + f * 4) = v;
    }
}

// ---------------------------------------------------------------------------
extern "C" void kernel_launch(void* const* d_in, const int* in_sizes, int n_in,
                              void* d_out, int out_size, void* d_ws, size_t ws_size,
                              hipStream_t stream) {
    const float* x     = (const float*)d_in[0];
    const float* w1    = (const float*)d_in[1];
    const float* b1    = (const float*)d_in[2];
    const float* gamma = (const float*)d_in[3];
    const float* beta  = (const float*)d_in[4];
    const float* w2    = (const float*)d_in[5];
    const float* b2    = (const float*)d_in[6];
    float* out = (float*)d_out;

    float* pooled = (float*)d_ws;                                   // 16*512 f32 = 32 KB
    int*   idx    = (int*)((char*)d_ws + Nn * Ww * sizeof(float));  // 16*128 i32 =  8 KB

    pool_kernel<<<Nn * Ww, 256, 0, stream>>>(x, pooled);
    mlp_topk_kernel<<<Nn, 512, 0, stream>>>(pooled, w1, b1, gamma, beta, w2, b2, idx);
    gather_kernel<<<Nn * OUTW, 256, 0, stream>>>(x, idx, out);
}